// Round 20
// baseline (627.792 us; speedup 1.0000x reference)
//
#include <hip/hip_runtime.h>
#include <hip/hip_bf16.h>

typedef __attribute__((ext_vector_type(8))) short bf16x8;
typedef __attribute__((ext_vector_type(4))) float f32x4;
typedef __attribute__((ext_vector_type(2))) long i64x2;

__device__ __forceinline__ float bf2f(short u) {
  union { unsigned int u; float f; } c;
  c.u = ((unsigned int)(unsigned short)u) << 16;
  return c.f;
}
__device__ __forceinline__ short f2bf(float f) {
  union { float f; unsigned int u; } c; c.f = f;
  unsigned int r = (c.u + 0x7fffu + ((c.u >> 16) & 1u)) >> 16;
  return (short)(unsigned short)r;
}

// exact e4m3fn -> f32 decode (bit trick; subnormals exact; no NaN inputs)
__device__ __forceinline__ float fp8_dec(unsigned b) {
  union { unsigned u; float f; } c;
  c.u = (b & 0x7fu) << 20;
  float v = c.f * 1.329227995784916e+36f;   // 2^120
  return (b & 0x80u) ? -v : v;
}

__device__ __forceinline__ void gload16(const void* g, void* l) {
  __builtin_amdgcn_global_load_lds(
      (const __attribute__((address_space(1))) unsigned int*)g,
      (__attribute__((address_space(3))) unsigned int*)l, 16, 0, 0);
}

// fp8 interleave within a 64-k group: logical k -> stored byte
__device__ __forceinline__ int fp8_g(int s) {
  return (s >> 6) * 64 + ((s >> 3) & 3) * 16 + ((s >> 5) & 1) * 8 + (s & 7);
}

// ---------------- fp32 -> bf16 convert (x and y in one dispatch) ----------------
__global__ __launch_bounds__(256) void cvt2_k(const float* __restrict__ x,
                                              const float* __restrict__ y,
                                              short* __restrict__ xb,
                                              short* __restrict__ yb, int n4) {
  const float* in = blockIdx.z ? y : x;
  short* out = blockIdx.z ? yb : xb;
  int i = blockIdx.x * blockDim.x + threadIdx.x;
  const int stride = gridDim.x * blockDim.x;
  for (; i < n4; i += stride) {
    float4 v = ((const float4*)in)[i];
    short4 o;
    o.x = f2bf(v.x); o.y = f2bf(v.y); o.z = f2bf(v.z); o.w = f2bf(v.w);
    ((short4*)out)[i] = o;
  }
}

// ---------------- W [1024][1024] f32 -> W^T bf16 (3 weights, z-batched) ----------------
__global__ __launch_bounds__(256) void cvtT3_k(
    const float* __restrict__ Wq, const float* __restrict__ Wk,
    const float* __restrict__ Wv, short* __restrict__ Wqt,
    short* __restrict__ Wkt, short* __restrict__ Wvt) {
  const float* W = (blockIdx.z == 0) ? Wq : (blockIdx.z == 1) ? Wk : Wv;
  short* Wt = (blockIdx.z == 0) ? Wqt : (blockIdx.z == 1) ? Wkt : Wvt;
  __shared__ float tile[32][33];
  const int n0 = blockIdx.x * 32, k0 = blockIdx.y * 32;
  const int tr = threadIdx.x >> 5;
  const int tc = threadIdx.x & 31;
#pragma unroll
  for (int p = 0; p < 4; ++p)
    tile[p * 8 + tr][tc] = W[(long long)(k0 + p * 8 + tr) * 1024 + n0 + tc];
  __syncthreads();
#pragma unroll
  for (int p = 0; p < 4; ++p)
    Wt[(long long)(n0 + p * 8 + tr) * 1024 + k0 + tc] = f2bf(tile[tc][p * 8 + tr]);
}

// =====================================================================
// gemm256_k: 256x256x64 8-phase bf16 MFMA GEMM (R6 core, validated)
// Batched over z; bias X (z==0) or X2 (z==1).
// EPI 3: V^T fp8-e4m3 [b][f][G(s)], +bias[row].
// EPI 4: fp8-e4m3 row-major [row][G(col)], +bias[col]  (Q/K projections).
// =====================================================================

#define STG6(sp, ld8, dOff) do { \
  gload16((sp), Ls + (dOff)); \
  gload16((const char*)(sp) + (ld8), Ls + (dOff) + 512); } while (0)

#define RD_A6(BUF, QM) do { \
  _Pragma("unroll") \
  for (int mi = 0; mi < 4; ++mi) { \
    aR[mi][0] = *(const bf16x8*)(Ls + (BUF) + (QM)*8192 + arow + mi*1024 + aO0); \
    aR[mi][1] = *(const bf16x8*)(Ls + (BUF) + (QM)*8192 + arow + mi*1024 + aO1); \
  } } while (0)

#define RD_B6(DST, BUF, QN) do { \
  _Pragma("unroll") \
  for (int ni = 0; ni < 2; ++ni) { \
    DST[ni][0] = *(const bf16x8*)(Ls + (BUF) + 16384 + (QN)*8192 + brow + ni*1024 + aO0); \
    DST[ni][1] = *(const bf16x8*)(Ls + (BUF) + 16384 + (QN)*8192 + brow + ni*1024 + aO1); \
  } } while (0)

#define SYNCIN6 do { \
  __builtin_amdgcn_sched_barrier(0); \
  __builtin_amdgcn_s_barrier(); \
  asm volatile("s_waitcnt lgkmcnt(0)" ::: "memory"); \
  __builtin_amdgcn_sched_barrier(0); \
  __builtin_amdgcn_s_setprio(1); } while (0)

#define SYNCOUT6 do { \
  __builtin_amdgcn_s_setprio(0); \
  __builtin_amdgcn_s_barrier(); } while (0)

#define MF166(ACCQ, BB) do { \
  _Pragma("unroll") \
  for (int mi = 0; mi < 4; ++mi) { \
    _Pragma("unroll") \
    for (int ni = 0; ni < 2; ++ni) { \
      ACCQ[mi][ni] = __builtin_amdgcn_mfma_f32_16x16x32_bf16(aR[mi][0], BB[ni][0], ACCQ[mi][ni], 0, 0, 0); \
      ACCQ[mi][ni] = __builtin_amdgcn_mfma_f32_16x16x32_bf16(aR[mi][1], BB[ni][1], ACCQ[mi][ni], 0, 0, 0); \
    } \
  } } while (0)

template<int EPI>
__global__ __launch_bounds__(512) void gemm256_k(
    const short* __restrict__ A, const short* __restrict__ Bt,
    void* __restrict__ Cv, const float* __restrict__ X,
    const float* __restrict__ X2,
    int K, int lda, int ldb, int ldc,
    long long strA, long long strB, long long strC) {
  __shared__ __align__(16) short Ls[65536];   // 128 KiB

  const int lane = threadIdx.x & 63;
  const int w = threadIdx.x >> 6;
  const int wm = w >> 2, wn = w & 3;
  const int w1k = w * 1024;
  const int l15 = lane & 15;
  const int g4 = lane >> 4;
  const int p8 = lane & 7;
  const int r8 = lane >> 3;
  const int aO0 = (g4 ^ p8) << 3;
  const int aO1 = ((4 + g4) ^ p8) << 3;
  const int arow = (wm * 64 + l15) * 64;
  const int brow = (wn * 32 + l15) * 64;

  const int gx = gridDim.x, gy = gridDim.y;
  const int nwg = gx * gy * gridDim.z;
  int lid = blockIdx.x + gx * (blockIdx.y + gy * blockIdx.z);
  lid = (lid & 7) * (nwg >> 3) + (lid >> 3);
  const int bx = lid % gx;
  const int rem = lid / gx;
  const int by = rem % gy;
  const int bz = rem / gy;

  const int n0 = bx * 256;
  const int m0 = by * 256;
  const int nt = K >> 6;
  const int nit = nt >> 1;

  const float* Xs = bz ? X2 : X;

  const long long ldaB = 2LL * lda, ldbB = 2LL * ldb;
  const long long ldaB8 = 8 * ldaB, ldbB8 = 8 * ldbB;
  const long long hOffA = 128 * ldaB, hOffB = 128 * ldbB;

  const char* pA = (const char*)(A + bz * strA)
      + (long long)(m0 + w * 16 + r8) * ldaB + ((p8 ^ r8) << 4);
  const char* pB = (const char*)(Bt + bz * strB)
      + (long long)(n0 + w * 16 + r8) * ldbB + ((p8 ^ r8) << 4);

  f32x4 acc[2][2][4][2] = {};
  bf16x8 aR[4][2], bR0[2][2], bR1[2][2];

  STG6(pA,                 ldaB8, 0 + w1k);
  STG6(pA + hOffA,         ldaB8, 8192 + w1k);
  STG6(pB,                 ldbB8, 16384 + w1k);
  STG6(pB + hOffB,         ldbB8, 24576 + w1k);
  STG6(pA + 128,           ldaB8, 32768 + w1k);
  STG6(pA + 128 + hOffA,   ldaB8, 40960 + w1k);
  STG6(pB + 128,           ldbB8, 49152 + w1k);
  STG6(pB + 128 + hOffB,   ldbB8, 57344 + w1k);
  asm volatile("s_waitcnt vmcnt(8)" ::: "memory");
  __builtin_amdgcn_s_barrier();

  for (int j = 0; j < nit; ++j) {
    const bool st = (j + 1 < nit);

    RD_A6(0, 0); RD_B6(bR0, 0, 0);
    SYNCIN6; MF166(acc[0][0], bR0); SYNCOUT6;
    RD_B6(bR1, 0, 1);
    if (st) { STG6(pA + 256, ldaB8, 0 + w1k);
              STG6(pB + 256, ldbB8, 16384 + w1k); }
    SYNCIN6; MF166(acc[0][1], bR1); SYNCOUT6;
    RD_A6(0, 1);
    if (st) STG6(pB + 256 + hOffB, ldbB8, 24576 + w1k);
    SYNCIN6; MF166(acc[1][1], bR1); SYNCOUT6;
    if (st) STG6(pA + 256 + hOffA, ldaB8, 8192 + w1k);
    SYNCIN6; MF166(acc[1][0], bR0);
    __builtin_amdgcn_s_setprio(0);
    if (st) asm volatile("s_waitcnt vmcnt(8)" ::: "memory");
    else    asm volatile("s_waitcnt vmcnt(0)" ::: "memory");
    __builtin_amdgcn_s_barrier();

    RD_A6(32768, 0); RD_B6(bR0, 32768, 0);
    SYNCIN6; MF166(acc[0][0], bR0); SYNCOUT6;
    RD_B6(bR1, 32768, 1);
    if (st) { STG6(pA + 384, ldaB8, 32768 + w1k);
              STG6(pB + 384, ldbB8, 49152 + w1k); }
    SYNCIN6; MF166(acc[0][1], bR1); SYNCOUT6;
    RD_A6(32768, 1);
    if (st) STG6(pB + 384 + hOffB, ldbB8, 57344 + w1k);
    SYNCIN6; MF166(acc[1][1], bR1); SYNCOUT6;
    if (st) STG6(pA + 384 + hOffA, ldaB8, 40960 + w1k);
    SYNCIN6; MF166(acc[1][0], bR0);
    __builtin_amdgcn_s_setprio(0);
    if (st) asm volatile("s_waitcnt vmcnt(8)" ::: "memory");
    __builtin_amdgcn_s_barrier();

    pA += 256; pB += 256;
  }

  const int rB = g4 * 4;
  if (EPI == 3) {  // V^T fp8, [b][f=row][G(s)], n = b*2048 + s
    unsigned char* C = (unsigned char*)Cv;
#pragma unroll
    for (int qn = 0; qn < 2; ++qn)
#pragma unroll
      for (int ni = 0; ni < 2; ++ni) {
        const int col = n0 + qn * 128 + wn * 32 + ni * 16 + l15;
        const int b2 = col >> 11;
        const int s = col & 2047;
        const int gs = fp8_g(s);
#pragma unroll
        for (int qm = 0; qm < 2; ++qm)
#pragma unroll
          for (int mi = 0; mi < 4; ++mi)
#pragma unroll
            for (int r = 0; r < 4; ++r) {
              const int row = m0 + qm * 128 + wm * 64 + mi * 16 + rB + r;
              const float v = acc[qm][qn][mi][ni][r] + Xs[row];
              const unsigned d = __builtin_amdgcn_cvt_pk_fp8_f32(v, v, 0, false);
              C[(long long)b2 * 2097152 + (long long)row * 2048 + gs] =
                  (unsigned char)(d & 0xff);
            }
      }
  } else {  // EPI == 4: fp8 row-major [row][G(col)], +bias[col]
    unsigned char* C = (unsigned char*)Cv + bz * strC;
#pragma unroll
    for (int qn = 0; qn < 2; ++qn)
#pragma unroll
      for (int ni = 0; ni < 2; ++ni) {
        const int col = n0 + qn * 128 + wn * 32 + ni * 16 + l15;
        const int gs = fp8_g(col);
        const float bv = Xs[col];
#pragma unroll
        for (int qm = 0; qm < 2; ++qm)
#pragma unroll
          for (int mi = 0; mi < 4; ++mi)
#pragma unroll
            for (int r = 0; r < 4; ++r) {
              const int row = m0 + qm * 128 + wm * 64 + mi * 16 + rB + r;
              const float v = acc[qm][qn][mi][ni][r] + bv;
              const unsigned d = __builtin_amdgcn_cvt_pk_fp8_f32(v, v, 0, false);
              C[(long long)row * ldc + gs] = (unsigned char)(d & 0xff);
            }
      }
  }
}

// ---------- row softmax over 2048: fp8 logits in -> fp8 P (x256, interleaved) ----------
__global__ __launch_bounds__(256) void softmax8_k(const unsigned char* __restrict__ Sl8,
                                                  unsigned char* __restrict__ P8) {
  __shared__ float redm[4];
  __shared__ float reds[4];
  const long long row = blockIdx.x;
  const unsigned char* p = Sl8 + row * 2048;
  const int t = threadIdx.x;
  const int w = t >> 6, lane = t & 63;
  const unsigned long long v8 = *(const unsigned long long*)(p + t * 8);
  float f[8];
  float mx = -3.0e38f;
#pragma unroll
  for (int j = 0; j < 8; ++j) {
    f[j] = fp8_dec((unsigned)(v8 >> (8 * j)) & 0xffu);
    mx = fmaxf(mx, f[j]);
  }
#pragma unroll
  for (int o = 32; o > 0; o >>= 1) mx = fmaxf(mx, __shfl_xor(mx, o));
  if (lane == 0) redm[w] = mx;
  __syncthreads();
  mx = fmaxf(fmaxf(redm[0], redm[1]), fmaxf(redm[2], redm[3]));
  float s = 0.f;
#pragma unroll
  for (int j = 0; j < 8; ++j) { f[j] = __expf(f[j] - mx); s += f[j]; }
#pragma unroll
  for (int o = 32; o > 0; o >>= 1) s += __shfl_xor(s, o);
  if (lane == 0) reds[w] = s;
  __syncthreads();
  s = reds[0] + reds[1] + reds[2] + reds[3];
  const float inv = 256.0f / (s + 1e-6f);   // P' = 256 * P (e4m3 range fit)
  unsigned d0 = __builtin_amdgcn_cvt_pk_fp8_f32(f[0] * inv, f[1] * inv, 0, false);
  d0 = __builtin_amdgcn_cvt_pk_fp8_f32(f[2] * inv, f[3] * inv, d0, true);
  unsigned d1 = __builtin_amdgcn_cvt_pk_fp8_f32(f[4] * inv, f[5] * inv, 0, false);
  d1 = __builtin_amdgcn_cvt_pk_fp8_f32(f[6] * inv, f[7] * inv, d1, true);
  const int grp = t >> 3, pc = t & 7;
  unsigned char* dst = P8 + row * 2048 + grp * 64 + (pc & 3) * 16 + (pc >> 2) * 8;
  *(unsigned long long*)dst =
      (unsigned long long)d0 | ((unsigned long long)d1 << 32);
}

// =====================================================================
// g8x256_k: 256x256xBK64 fp8 MFMA GEMM, 16 waves (1024 thr), triple-
// buffered 96KB (R16 ledger: depth-3, vmcnt 4/2/0).  Wave-role staging:
// waves 0-7 stage A rows, 8-15 stage B rows (2 gload16/wave/tile).
// Per wave output 64x64 (acc 64 VGPR); 4M x 4N wave grid.
// EPI 1: fp8-e4m3 out (scale pre-convert) -> Sl8;  EPI 2: f32*scale + X.
// =====================================================================

template<int EPI>
__global__ __launch_bounds__(1024, 4) void g8x256_k(
    const unsigned char* __restrict__ A8, const unsigned char* __restrict__ B8,
    void* __restrict__ Cv, const float* __restrict__ X,
    int K, int ldaB, int ldbB, int ldc,
    long long strA, long long strB, long long strC, long long strX, float scale) {
  __shared__ __align__(16) char Ls[98304];   // 3 bufs x (A 16KB + B 16KB)

  const int lane = threadIdx.x & 63;
  const int w = threadIdx.x >> 6;       // 0..15
  const int wm = w >> 2, wn = w & 3;
  const int l15 = lane & 15;
  const int g4 = lane >> 4;
  const int swB = ((g4 ^ ((l15 >> 1) & 3)) << 4);   // byte slot offset
  const int arow = (wm * 64 + l15) * 64 + swB;
  const int brow = (wn * 64 + l15) * 64 + swB;
  const int sg = (lane & 3) ^ ((lane >> 3) & 3);

  const int gx = gridDim.x, gy = gridDim.y;
  const int nwg = gx * gy * gridDim.z;
  int lid = blockIdx.x + gx * (blockIdx.y + gy * blockIdx.z);
  lid = (lid & 7) * (nwg >> 3) + (lid >> 3);
  const int bx = lid % gx;
  const int rem = lid / gx;
  const int by = rem % gy;
  const int bz = rem / gy;
  const int n0 = bx * 256, m0 = by * 256;
  const int nt = K >> 6;

  const long long ldaL = ldaB, ldbL = ldbB;
  // wave-role staging pointers (2 gload16/wave/tile, 32 rows per wave)
  const bool isA = (w < 8);
  const int wS = isA ? w : (w - 8);
  const char* pS = isA
      ? ((const char*)A8 + bz * strA
         + (long long)(m0 + wS * 32 + (lane >> 2)) * ldaL + sg * 16)
      : ((const char*)B8 + bz * strB
         + (long long)(n0 + wS * 32 + (lane >> 2)) * ldbL + sg * 16);
  const long long ld16S = 16 * (isA ? ldaL : ldbL);
  char* dS = Ls + (isA ? 0 : 16384) + wS * 2048;   // + buf*32768

  f32x4 acc[4][4] = {};

  // prologue: stage tiles 0,1,2 -> buffers 0,1,2 (2 loads/wave each)
#pragma unroll
  for (int i = 0; i < 3; ++i) {
    gload16(pS + i * 64,         dS + i * 32768);
    gload16(pS + i * 64 + ld16S, dS + i * 32768 + 1024);
  }
  asm volatile("s_waitcnt vmcnt(4)" ::: "memory");   // tile0 landed
  __builtin_amdgcn_s_barrier();

  int cur = 0;
  for (int t = 0; t < nt; ++t) {
    const int bufO = cur * 32768;
    i64x2 aA[4], bB[4];
#pragma unroll
    for (int mi = 0; mi < 4; ++mi)
      aA[mi] = *(const i64x2*)(Ls + bufO + arow + mi * 1024);
#pragma unroll
    for (int ni = 0; ni < 4; ++ni)
      bB[ni] = *(const i64x2*)(Ls + bufO + 16384 + brow + ni * 1024);
    asm volatile("s_waitcnt lgkmcnt(0)" ::: "memory");
    __builtin_amdgcn_s_barrier();
    if (t + 3 < nt) {
      gload16(pS + (t + 3) * 64,         dS + bufO);
      gload16(pS + (t + 3) * 64 + ld16S, dS + bufO + 1024);
    }
    __builtin_amdgcn_sched_barrier(0);
    __builtin_amdgcn_s_setprio(1);
#pragma unroll
    for (int mi = 0; mi < 4; ++mi)
#pragma unroll
      for (int ni = 0; ni < 4; ++ni) {
        acc[mi][ni] = __builtin_amdgcn_mfma_f32_16x16x32_fp8_fp8(
            aA[mi][0], bB[ni][0], acc[mi][ni], 0, 0, 0);
        acc[mi][ni] = __builtin_amdgcn_mfma_f32_16x16x32_fp8_fp8(
            aA[mi][1], bB[ni][1], acc[mi][ni], 0, 0, 0);
      }
    __builtin_amdgcn_s_setprio(0);
    if (t + 3 < nt)      asm volatile("s_waitcnt vmcnt(4)" ::: "memory");
    else if (t + 2 < nt) asm volatile("s_waitcnt vmcnt(2)" ::: "memory");
    else                 asm volatile("s_waitcnt vmcnt(0)" ::: "memory");
    __builtin_amdgcn_s_barrier();
    cur = (cur == 2) ? 0 : cur + 1;
  }

  const int rB = g4 * 4;
  if (EPI == 1) {  // Sl8 = e4m3(acc * scale), row-major bytes
    unsigned char* C = (unsigned char*)Cv + bz * strC;
#pragma unroll
    for (int ni = 0; ni < 4; ++ni) {
      const int col = n0 + wn * 64 + ni * 16 + l15;
#pragma unroll
      for (int mi = 0; mi < 4; ++mi)
#pragma unroll
        for (int r = 0; r < 4; ++r) {
          const int row = m0 + wm * 64 + mi * 16 + rB + r;
          const float v = acc[mi][ni][r] * scale;
          const unsigned d = __builtin_amdgcn_cvt_pk_fp8_f32(v, v, 0, false);
          C[(long long)row * ldc + col] = (unsigned char)(d & 0xff);
        }
    }
  } else {  // EPI == 2
    float* C = (float*)Cv + bz * strC;
    const float* Xb = X + bz * strX;
#pragma unroll
    for (int ni = 0; ni < 4; ++ni) {
      const int col = n0 + wn * 64 + ni * 16 + l15;
#pragma unroll
      for (int mi = 0; mi < 4; ++mi)
#pragma unroll
        for (int r = 0; r < 4; ++r) {
          const int row = m0 + wm * 64 + mi * 16 + rB + r;
          const long long idx = (long long)row * ldc + col;
          C[idx] = acc[mi][ni][r] * scale + Xb[idx];
        }
    }
  }
}

extern "C" void kernel_launch(void* const* d_in, const int* in_sizes, int n_in,
                              void* d_out, int out_size, void* d_ws, size_t ws_size,
                              hipStream_t stream) {
  const float* x  = (const float*)d_in[0];
  const float* y  = (const float*)d_in[1];
  const float* Wq = (const float*)d_in[2];
  const float* bq = (const float*)d_in[3];
  const float* Wk = (const float*)d_in[4];
  const float* bk = (const float*)d_in[5];
  const float* Wv = (const float*)d_in[6];
  const float* bv = (const float*)d_in[7];
  float* out = (float*)d_out;

  const long long SD  = 2048LL * 1024;
  const long long BSD = 16LL * SD;
  const long long SS  = 2048LL * 2048;

  char* ws = (char*)d_ws;
  short* xb  = (short*)ws;                   // 67.1 MB (yb contiguous after)
  short* yb  = xb + BSD;                     // 67.1 MB
  unsigned char* Sl8 = (unsigned char*)ws;   // 67.1 MB fp8 (aliases xb; dead then)
  unsigned char* Q8 = (unsigned char*)(ws + 134217728);  // 33.5 MB fp8
  unsigned char* K8 = (unsigned char*)(ws + 167772160);  // 33.5 MB fp8 (Q8+stride)
  unsigned char* P8 = Q8;                    // 67.1 MB fp8 (overwrites Q8+K8, both dead)
  unsigned char* V8 = (unsigned char*)(ws + 268435456);  // 33.5 MB fp8
  short* Wqt = (short*)(ws + 335544320);     // 2 MB each, contiguous
  short* Wkt = Wqt + 1024 * 1024;
  short* Wvt = Wkt + 1024 * 1024;

  // 1) convert x, y to bf16 (one dispatch)
  cvt2_k<<<dim3(2048, 1, 2), 256, 0, stream>>>(x, y, xb, yb, (int)(BSD / 4));

  // 2) transpose+convert all three weights (one dispatch)
  cvtT3_k<<<dim3(32, 32, 3), 256, 0, stream>>>(Wq, Wk, Wv, Wqt, Wkt, Wvt);

  // 3+4) Q8/K8 projections batched: z=0: xb@Wqt+bq -> Q8; z=1: yb@Wkt+bk -> K8
  gemm256_k<4><<<dim3(4, 128, 2), 512, 0, stream>>>(
      xb, Wqt, Q8, bq, bk, 1024, 1024, 1024, 1024,
      BSD, 1048576LL, 33554432LL);

  // 5) V8 = e4m3(V^T): A = Wv^T, Bt = yb -> [b][f][G(s)]
  gemm256_k<3><<<dim3(128, 4, 1), 512, 0, stream>>>(
      Wvt, yb, V8, bv, nullptr, 1024, 1024, 1024, 0, 0, 0, 0);

  // 6) Sl8 = e4m3((Q8 @ K8^T)/32)   (fp8 256^2 GEMM, K=1024)
  g8x256_k<1><<<dim3(8, 8, 16), 1024, 0, stream>>>(
      Q8, K8, Sl8, nullptr, 1024, 1024, 1024, 2048,
      2097152LL, 2097152LL, SS, 0, 0.03125f);

  // 7) softmax rows (fp8 in) -> P8 = e4m3(256 * P), k-interleaved
  softmax8_k<<<32768, 256, 0, stream>>>(Sl8, P8);

  // 8) out = (P8 @ V8) / 256 + x   (fp8 256^2 GEMM, K=2048)
  g8x256_k<2><<<dim3(4, 8, 16), 1024, 0, stream>>>(
      P8, V8, out, x, 2048, 2048, 2048, 1024,
      4194304LL, 2097152LL, SD, SD, 0.00390625f);

  (void)in_sizes; (void)n_in; (void)out_size; (void)ws_size;
}

// Round 21
// 601.694 us; speedup vs baseline: 1.0434x; 1.0434x over previous
//
#include <hip/hip_runtime.h>
#include <hip/hip_bf16.h>

typedef __attribute__((ext_vector_type(8))) short bf16x8;
typedef __attribute__((ext_vector_type(4))) float f32x4;
typedef __attribute__((ext_vector_type(2))) long i64x2;

__device__ __forceinline__ float bf2f(short u) {
  union { unsigned int u; float f; } c;
  c.u = ((unsigned int)(unsigned short)u) << 16;
  return c.f;
}
__device__ __forceinline__ short f2bf(float f) {
  union { float f; unsigned int u; } c; c.f = f;
  unsigned int r = (c.u + 0x7fffu + ((c.u >> 16) & 1u)) >> 16;
  return (short)(unsigned short)r;
}

// exact e4m3fn -> f32 decode (bit trick; subnormals exact; no NaN inputs)
__device__ __forceinline__ float fp8_dec(unsigned b) {
  union { unsigned u; float f; } c;
  c.u = (b & 0x7fu) << 20;
  float v = c.f * 1.329227995784916e+36f;   // 2^120
  return (b & 0x80u) ? -v : v;
}

__device__ __forceinline__ void gload16(const void* g, void* l) {
  __builtin_amdgcn_global_load_lds(
      (const __attribute__((address_space(1))) unsigned int*)g,
      (__attribute__((address_space(3))) unsigned int*)l, 16, 0, 0);
}

// fp8 interleave within a 64-k group: logical k -> stored byte
__device__ __forceinline__ int fp8_g(int s) {
  return (s >> 6) * 64 + ((s >> 3) & 3) * 16 + ((s >> 5) & 1) * 8 + (s & 7);
}

// ---------------- fp32 -> bf16 convert (x and y in one dispatch) ----------------
__global__ __launch_bounds__(256) void cvt2_k(const float* __restrict__ x,
                                              const float* __restrict__ y,
                                              short* __restrict__ xb,
                                              short* __restrict__ yb, int n4) {
  const float* in = blockIdx.z ? y : x;
  short* out = blockIdx.z ? yb : xb;
  int i = blockIdx.x * blockDim.x + threadIdx.x;
  const int stride = gridDim.x * blockDim.x;
  for (; i < n4; i += stride) {
    float4 v = ((const float4*)in)[i];
    short4 o;
    o.x = f2bf(v.x); o.y = f2bf(v.y); o.z = f2bf(v.z); o.w = f2bf(v.w);
    ((short4*)out)[i] = o;
  }
}

// ---------------- W [1024][1024] f32 -> W^T bf16 (3 weights, z-batched) ----------------
__global__ __launch_bounds__(256) void cvtT3_k(
    const float* __restrict__ Wq, const float* __restrict__ Wk,
    const float* __restrict__ Wv, short* __restrict__ Wqt,
    short* __restrict__ Wkt, short* __restrict__ Wvt) {
  const float* W = (blockIdx.z == 0) ? Wq : (blockIdx.z == 1) ? Wk : Wv;
  short* Wt = (blockIdx.z == 0) ? Wqt : (blockIdx.z == 1) ? Wkt : Wvt;
  __shared__ float tile[32][33];
  const int n0 = blockIdx.x * 32, k0 = blockIdx.y * 32;
  const int tr = threadIdx.x >> 5;
  const int tc = threadIdx.x & 31;
#pragma unroll
  for (int p = 0; p < 4; ++p)
    tile[p * 8 + tr][tc] = W[(long long)(k0 + p * 8 + tr) * 1024 + n0 + tc];
  __syncthreads();
#pragma unroll
  for (int p = 0; p < 4; ++p)
    Wt[(long long)(n0 + p * 8 + tr) * 1024 + k0 + tc] = f2bf(tile[tc][p * 8 + tr]);
}

// =====================================================================
// gemm256_k: 256x256x64 8-phase bf16 MFMA GEMM (R6 core, validated)
// Batched over z with element strides strA/strB (shorts), strC (bytes);
// bias X (z==0) or X2 (z==1).
// EPI 3: V^T fp8-e4m3 [b][f][G(s)], +bias[row].
// EPI 4: fp8-e4m3 row-major [row][G(col)], +bias[col]  (Q/K projections).
// =====================================================================

#define STG6(sp, ld8, dOff) do { \
  gload16((sp), Ls + (dOff)); \
  gload16((const char*)(sp) + (ld8), Ls + (dOff) + 512); } while (0)

#define RD_A6(BUF, QM) do { \
  _Pragma("unroll") \
  for (int mi = 0; mi < 4; ++mi) { \
    aR[mi][0] = *(const bf16x8*)(Ls + (BUF) + (QM)*8192 + arow + mi*1024 + aO0); \
    aR[mi][1] = *(const bf16x8*)(Ls + (BUF) + (QM)*8192 + arow + mi*1024 + aO1); \
  } } while (0)

#define RD_B6(DST, BUF, QN) do { \
  _Pragma("unroll") \
  for (int ni = 0; ni < 2; ++ni) { \
    DST[ni][0] = *(const bf16x8*)(Ls + (BUF) + 16384 + (QN)*8192 + brow + ni*1024 + aO0); \
    DST[ni][1] = *(const bf16x8*)(Ls + (BUF) + 16384 + (QN)*8192 + brow + ni*1024 + aO1); \
  } } while (0)

#define SYNCIN6 do { \
  __builtin_amdgcn_sched_barrier(0); \
  __builtin_amdgcn_s_barrier(); \
  asm volatile("s_waitcnt lgkmcnt(0)" ::: "memory"); \
  __builtin_amdgcn_sched_barrier(0); \
  __builtin_amdgcn_s_setprio(1); } while (0)

#define SYNCOUT6 do { \
  __builtin_amdgcn_s_setprio(0); \
  __builtin_amdgcn_s_barrier(); } while (0)

#define MF166(ACCQ, BB) do { \
  _Pragma("unroll") \
  for (int mi = 0; mi < 4; ++mi) { \
    _Pragma("unroll") \
    for (int ni = 0; ni < 2; ++ni) { \
      ACCQ[mi][ni] = __builtin_amdgcn_mfma_f32_16x16x32_bf16(aR[mi][0], BB[ni][0], ACCQ[mi][ni], 0, 0, 0); \
      ACCQ[mi][ni] = __builtin_amdgcn_mfma_f32_16x16x32_bf16(aR[mi][1], BB[ni][1], ACCQ[mi][ni], 0, 0, 0); \
    } \
  } } while (0)

template<int EPI>
__global__ __launch_bounds__(512) void gemm256_k(
    const short* __restrict__ A, const short* __restrict__ Bt,
    void* __restrict__ Cv, const float* __restrict__ X,
    const float* __restrict__ X2,
    int K, int lda, int ldb, int ldc,
    long long strA, long long strB, long long strC) {
  __shared__ __align__(16) short Ls[65536];   // 128 KiB

  const int lane = threadIdx.x & 63;
  const int w = threadIdx.x >> 6;
  const int wm = w >> 2, wn = w & 3;
  const int w1k = w * 1024;
  const int l15 = lane & 15;
  const int g4 = lane >> 4;
  const int p8 = lane & 7;
  const int r8 = lane >> 3;
  const int aO0 = (g4 ^ p8) << 3;
  const int aO1 = ((4 + g4) ^ p8) << 3;
  const int arow = (wm * 64 + l15) * 64;
  const int brow = (wn * 32 + l15) * 64;

  const int gx = gridDim.x, gy = gridDim.y;
  const int nwg = gx * gy * gridDim.z;
  int lid = blockIdx.x + gx * (blockIdx.y + gy * blockIdx.z);
  lid = (lid & 7) * (nwg >> 3) + (lid >> 3);
  const int bx = lid % gx;
  const int rem = lid / gx;
  const int by = rem % gy;
  const int bz = rem / gy;

  const int n0 = bx * 256;
  const int m0 = by * 256;
  const int nt = K >> 6;
  const int nit = nt >> 1;

  const float* Xs = bz ? X2 : X;

  const long long ldaB = 2LL * lda, ldbB = 2LL * ldb;
  const long long ldaB8 = 8 * ldaB, ldbB8 = 8 * ldbB;
  const long long hOffA = 128 * ldaB, hOffB = 128 * ldbB;

  const char* pA = (const char*)(A + bz * strA)
      + (long long)(m0 + w * 16 + r8) * ldaB + ((p8 ^ r8) << 4);
  const char* pB = (const char*)(Bt + bz * strB)
      + (long long)(n0 + w * 16 + r8) * ldbB + ((p8 ^ r8) << 4);

  f32x4 acc[2][2][4][2] = {};
  bf16x8 aR[4][2], bR0[2][2], bR1[2][2];

  STG6(pA,                 ldaB8, 0 + w1k);
  STG6(pA + hOffA,         ldaB8, 8192 + w1k);
  STG6(pB,                 ldbB8, 16384 + w1k);
  STG6(pB + hOffB,         ldbB8, 24576 + w1k);
  STG6(pA + 128,           ldaB8, 32768 + w1k);
  STG6(pA + 128 + hOffA,   ldaB8, 40960 + w1k);
  STG6(pB + 128,           ldbB8, 49152 + w1k);
  STG6(pB + 128 + hOffB,   ldbB8, 57344 + w1k);
  asm volatile("s_waitcnt vmcnt(8)" ::: "memory");
  __builtin_amdgcn_s_barrier();

  for (int j = 0; j < nit; ++j) {
    const bool st = (j + 1 < nit);

    RD_A6(0, 0); RD_B6(bR0, 0, 0);
    SYNCIN6; MF166(acc[0][0], bR0); SYNCOUT6;
    RD_B6(bR1, 0, 1);
    if (st) { STG6(pA + 256, ldaB8, 0 + w1k);
              STG6(pB + 256, ldbB8, 16384 + w1k); }
    SYNCIN6; MF166(acc[0][1], bR1); SYNCOUT6;
    RD_A6(0, 1);
    if (st) STG6(pB + 256 + hOffB, ldbB8, 24576 + w1k);
    SYNCIN6; MF166(acc[1][1], bR1); SYNCOUT6;
    if (st) STG6(pA + 256 + hOffA, ldaB8, 8192 + w1k);
    SYNCIN6; MF166(acc[1][0], bR0);
    __builtin_amdgcn_s_setprio(0);
    if (st) asm volatile("s_waitcnt vmcnt(8)" ::: "memory");
    else    asm volatile("s_waitcnt vmcnt(0)" ::: "memory");
    __builtin_amdgcn_s_barrier();

    RD_A6(32768, 0); RD_B6(bR0, 32768, 0);
    SYNCIN6; MF166(acc[0][0], bR0); SYNCOUT6;
    RD_B6(bR1, 32768, 1);
    if (st) { STG6(pA + 384, ldaB8, 32768 + w1k);
              STG6(pB + 384, ldbB8, 49152 + w1k); }
    SYNCIN6; MF166(acc[0][1], bR1); SYNCOUT6;
    RD_A6(32768, 1);
    if (st) STG6(pB + 384 + hOffB, ldbB8, 57344 + w1k);
    SYNCIN6; MF166(acc[1][1], bR1); SYNCOUT6;
    if (st) STG6(pA + 384 + hOffA, ldaB8, 40960 + w1k);
    SYNCIN6; MF166(acc[1][0], bR0);
    __builtin_amdgcn_s_setprio(0);
    if (st) asm volatile("s_waitcnt vmcnt(8)" ::: "memory");
    __builtin_amdgcn_s_barrier();

    pA += 256; pB += 256;
  }

  const int rB = g4 * 4;
  if (EPI == 3) {  // V^T fp8, [b][f=row][G(s)], n = b*2048 + s
    unsigned char* C = (unsigned char*)Cv;
#pragma unroll
    for (int qn = 0; qn < 2; ++qn)
#pragma unroll
      for (int ni = 0; ni < 2; ++ni) {
        const int col = n0 + qn * 128 + wn * 32 + ni * 16 + l15;
        const int b2 = col >> 11;
        const int s = col & 2047;
        const int gs = fp8_g(s);
#pragma unroll
        for (int qm = 0; qm < 2; ++qm)
#pragma unroll
          for (int mi = 0; mi < 4; ++mi)
#pragma unroll
            for (int r = 0; r < 4; ++r) {
              const int row = m0 + qm * 128 + wm * 64 + mi * 16 + rB + r;
              const float v = acc[qm][qn][mi][ni][r] + Xs[row];
              const unsigned d = __builtin_amdgcn_cvt_pk_fp8_f32(v, v, 0, false);
              C[(long long)b2 * 2097152 + (long long)row * 2048 + gs] =
                  (unsigned char)(d & 0xff);
            }
      }
  } else {  // EPI == 4: fp8 row-major [row][G(col)], +bias[col]
    unsigned char* C = (unsigned char*)Cv + bz * strC;
#pragma unroll
    for (int qn = 0; qn < 2; ++qn)
#pragma unroll
      for (int ni = 0; ni < 2; ++ni) {
        const int col = n0 + qn * 128 + wn * 32 + ni * 16 + l15;
        const int gs = fp8_g(col);
        const float bv = Xs[col];
#pragma unroll
        for (int qm = 0; qm < 2; ++qm)
#pragma unroll
          for (int mi = 0; mi < 4; ++mi)
#pragma unroll
            for (int r = 0; r < 4; ++r) {
              const int row = m0 + qm * 128 + wm * 64 + mi * 16 + rB + r;
              const float v = acc[qm][qn][mi][ni][r] + bv;
              const unsigned d = __builtin_amdgcn_cvt_pk_fp8_f32(v, v, 0, false);
              C[(long long)row * ldc + gs] = (unsigned char)(d & 0xff);
            }
      }
  }
}

// ---------- row softmax over 2048: fp8 logits in -> fp8 P (x256, interleaved) ----------
__global__ __launch_bounds__(256) void softmax8_k(const unsigned char* __restrict__ Sl8,
                                                  unsigned char* __restrict__ P8) {
  __shared__ float redm[4];
  __shared__ float reds[4];
  const long long row = blockIdx.x;
  const unsigned char* p = Sl8 + row * 2048;
  const int t = threadIdx.x;
  const int w = t >> 6, lane = t & 63;
  const unsigned long long v8 = *(const unsigned long long*)(p + t * 8);
  float f[8];
  float mx = -3.0e38f;
#pragma unroll
  for (int j = 0; j < 8; ++j) {
    f[j] = fp8_dec((unsigned)(v8 >> (8 * j)) & 0xffu);
    mx = fmaxf(mx, f[j]);
  }
#pragma unroll
  for (int o = 32; o > 0; o >>= 1) mx = fmaxf(mx, __shfl_xor(mx, o));
  if (lane == 0) redm[w] = mx;
  __syncthreads();
  mx = fmaxf(fmaxf(redm[0], redm[1]), fmaxf(redm[2], redm[3]));
  float s = 0.f;
#pragma unroll
  for (int j = 0; j < 8; ++j) { f[j] = __expf(f[j] - mx); s += f[j]; }
#pragma unroll
  for (int o = 32; o > 0; o >>= 1) s += __shfl_xor(s, o);
  if (lane == 0) reds[w] = s;
  __syncthreads();
  s = reds[0] + reds[1] + reds[2] + reds[3];
  const float inv = 256.0f / (s + 1e-6f);   // P' = 256 * P (e4m3 range fit)
  unsigned d0 = __builtin_amdgcn_cvt_pk_fp8_f32(f[0] * inv, f[1] * inv, 0, false);
  d0 = __builtin_amdgcn_cvt_pk_fp8_f32(f[2] * inv, f[3] * inv, d0, true);
  unsigned d1 = __builtin_amdgcn_cvt_pk_fp8_f32(f[4] * inv, f[5] * inv, 0, false);
  d1 = __builtin_amdgcn_cvt_pk_fp8_f32(f[6] * inv, f[7] * inv, d1, true);
  const int grp = t >> 3, pc = t & 7;
  unsigned char* dst = P8 + row * 2048 + grp * 64 + (pc & 3) * 16 + (pc >> 2) * 8;
  *(unsigned long long*)dst =
      (unsigned long long)d0 | ((unsigned long long)d1 << 32);
}

// =====================================================================
// g8fp8_k: 256x128xBK64 fp8 MFMA GEMM, triple-buffered (R16 core).
// EPI 1: fp8-e4m3 out (scale applied pre-convert) -> Sl8 (QK^T);
// EPI 2: f32 out * scale + X (PV + residual).
// =====================================================================

template<int EPI>
__global__ __launch_bounds__(512, 4) void g8fp8_k(
    const unsigned char* __restrict__ A8, const unsigned char* __restrict__ B8,
    void* __restrict__ Cv, const float* __restrict__ X,
    int K, int ldaB, int ldbB, int ldc,
    long long strA, long long strB, long long strC, long long strX, float scale) {
  __shared__ __align__(16) char Ls[73728];   // 3 bufs x (A 16KB + B 8KB)

  const int lane = threadIdx.x & 63;
  const int w = threadIdx.x >> 6;
  const int wm = w >> 1, wn = w & 1;
  const int l15 = lane & 15;
  const int g4 = lane >> 4;
  const int swB = ((g4 ^ ((l15 >> 1) & 3)) << 4);   // byte slot offset
  const int arow = (wm * 64 + l15) * 64 + swB;
  const int brow = (wn * 64 + l15) * 64 + swB;
  const int sg = (lane & 3) ^ ((lane >> 3) & 3);

  const int gx = gridDim.x, gy = gridDim.y;
  const int nwg = gx * gy * gridDim.z;
  int lid = blockIdx.x + gx * (blockIdx.y + gy * blockIdx.z);
  lid = (lid & 7) * (nwg >> 3) + (lid >> 3);
  const int bx = lid % gx;
  const int rem = lid / gx;
  const int by = rem % gy;
  const int bz = rem / gy;
  const int n0 = bx * 128, m0 = by * 256;
  const int nt = K >> 6;

  const long long ldaL = ldaB, ldbL = ldbB;
  const char* pA = (const char*)A8 + bz * strA
      + (long long)(m0 + w * 32 + (lane >> 2)) * ldaL + sg * 16;
  const char* pB = (const char*)B8 + bz * strB
      + (long long)(n0 + w * 16 + (lane >> 2)) * ldbL + sg * 16;
  const long long ldaL16 = 16 * ldaL;

  char* dA = Ls + w * 2048;             // + buf*24576
  char* dB = Ls + 16384 + w * 1024;     // + buf*24576

  f32x4 acc[4][4] = {};

#pragma unroll
  for (int i = 0; i < 3; ++i) {
    const char* qA = pA + i * 64;
    gload16(qA,           dA + i * 24576);
    gload16(qA + ldaL16,  dA + i * 24576 + 1024);
    gload16(pB + i * 64,  dB + i * 24576);
  }
  asm volatile("s_waitcnt vmcnt(6)" ::: "memory");
  __builtin_amdgcn_s_barrier();

  int cur = 0;
  for (int t = 0; t < nt; ++t) {
    const int bufO = cur * 24576;
    i64x2 aA[4], bB[4];
#pragma unroll
    for (int mi = 0; mi < 4; ++mi)
      aA[mi] = *(const i64x2*)(Ls + bufO + arow + mi * 1024);
#pragma unroll
    for (int ni = 0; ni < 4; ++ni)
      bB[ni] = *(const i64x2*)(Ls + bufO + 16384 + brow + ni * 1024);
    asm volatile("s_waitcnt lgkmcnt(0)" ::: "memory");
    __builtin_amdgcn_s_barrier();
    if (t + 3 < nt) {
      const char* qA = pA + (t + 3) * 64;
      gload16(qA,          dA + bufO);
      gload16(qA + ldaL16, dA + bufO + 1024);
      gload16(pB + (t + 3) * 64, dB + bufO);
    }
    __builtin_amdgcn_sched_barrier(0);
    __builtin_amdgcn_s_setprio(1);
#pragma unroll
    for (int mi = 0; mi < 4; ++mi)
#pragma unroll
      for (int ni = 0; ni < 4; ++ni) {
        acc[mi][ni] = __builtin_amdgcn_mfma_f32_16x16x32_fp8_fp8(
            aA[mi][0], bB[ni][0], acc[mi][ni], 0, 0, 0);
        acc[mi][ni] = __builtin_amdgcn_mfma_f32_16x16x32_fp8_fp8(
            aA[mi][1], bB[ni][1], acc[mi][ni], 0, 0, 0);
      }
    __builtin_amdgcn_s_setprio(0);
    if (t + 3 < nt)      asm volatile("s_waitcnt vmcnt(6)" ::: "memory");
    else if (t + 2 < nt) asm volatile("s_waitcnt vmcnt(3)" ::: "memory");
    else                 asm volatile("s_waitcnt vmcnt(0)" ::: "memory");
    __builtin_amdgcn_s_barrier();
    cur = (cur == 2) ? 0 : cur + 1;
  }

  const int rB = g4 * 4;
  if (EPI == 1) {  // Sl8 = e4m3(acc * scale), row-major bytes
    unsigned char* C = (unsigned char*)Cv + bz * strC;
#pragma unroll
    for (int ni = 0; ni < 4; ++ni) {
      const int col = n0 + wn * 64 + ni * 16 + l15;
#pragma unroll
      for (int mi = 0; mi < 4; ++mi)
#pragma unroll
        for (int r = 0; r < 4; ++r) {
          const int row = m0 + wm * 64 + mi * 16 + rB + r;
          const float v = acc[mi][ni][r] * scale;
          const unsigned d = __builtin_amdgcn_cvt_pk_fp8_f32(v, v, 0, false);
          C[(long long)row * ldc + col] = (unsigned char)(d & 0xff);
        }
    }
  } else {  // EPI == 2
    float* C = (float*)Cv + bz * strC;
    const float* Xb = X + bz * strX;
#pragma unroll
    for (int ni = 0; ni < 4; ++ni) {
      const int col = n0 + wn * 64 + ni * 16 + l15;
#pragma unroll
      for (int mi = 0; mi < 4; ++mi)
#pragma unroll
        for (int r = 0; r < 4; ++r) {
          const int row = m0 + wm * 64 + mi * 16 + rB + r;
          const long long idx = (long long)row * ldc + col;
          C[idx] = acc[mi][ni][r] * scale + Xb[idx];
        }
    }
  }
}

extern "C" void kernel_launch(void* const* d_in, const int* in_sizes, int n_in,
                              void* d_out, int out_size, void* d_ws, size_t ws_size,
                              hipStream_t stream) {
  const float* x  = (const float*)d_in[0];
  const float* y  = (const float*)d_in[1];
  const float* Wq = (const float*)d_in[2];
  const float* bq = (const float*)d_in[3];
  const float* Wk = (const float*)d_in[4];
  const float* bk = (const float*)d_in[5];
  const float* Wv = (const float*)d_in[6];
  const float* bv = (const float*)d_in[7];
  float* out = (float*)d_out;

  const long long SD  = 2048LL * 1024;
  const long long BSD = 16LL * SD;
  const long long SS  = 2048LL * 2048;

  char* ws = (char*)d_ws;
  short* xb  = (short*)ws;                   // 67.1 MB (yb contiguous after)
  short* yb  = xb + BSD;                     // 67.1 MB
  unsigned char* Sl8 = (unsigned char*)ws;   // 67.1 MB fp8 (aliases xb; dead then)
  unsigned char* Q8 = (unsigned char*)(ws + 134217728);  // 33.5 MB fp8
  unsigned char* K8 = (unsigned char*)(ws + 167772160);  // 33.5 MB fp8 (Q8+stride)
  unsigned char* P8 = Q8;                    // 67.1 MB fp8 (overwrites Q8+K8, both dead)
  unsigned char* V8 = (unsigned char*)(ws + 268435456);  // 33.5 MB fp8
  short* Wqt = (short*)(ws + 335544320);     // 2 MB each, contiguous
  short* Wkt = Wqt + 1024 * 1024;
  short* Wvt = Wkt + 1024 * 1024;

  // 1) convert x, y to bf16 (one dispatch)
  cvt2_k<<<dim3(2048, 1, 2), 256, 0, stream>>>(x, y, xb, yb, (int)(BSD / 4));

  // 2) transpose+convert all three weights (one dispatch)
  cvtT3_k<<<dim3(32, 32, 3), 256, 0, stream>>>(Wq, Wk, Wv, Wqt, Wkt, Wvt);

  // 3+4) Q8/K8 projections batched: z=0: xb@Wqt+bq -> Q8; z=1: yb@Wkt+bk -> K8
  gemm256_k<4><<<dim3(4, 128, 2), 512, 0, stream>>>(
      xb, Wqt, Q8, bq, bk, 1024, 1024, 1024, 1024,
      BSD, 1048576LL, 33554432LL);

  // 5) V8 = e4m3(V^T): A = Wv^T, Bt = yb -> [b][f][G(s)]
  gemm256_k<3><<<dim3(128, 4, 1), 512, 0, stream>>>(
      Wvt, yb, V8, bv, nullptr, 1024, 1024, 1024, 0, 0, 0, 0);

  // 6) Sl8 = e4m3((Q8 @ K8^T)/32)   (fp8 GEMM, K=1024)
  g8fp8_k<1><<<dim3(16, 8, 16), 512, 0, stream>>>(
      Q8, K8, Sl8, nullptr, 1024, 1024, 1024, 2048,
      2097152LL, 2097152LL, SS, 0, 0.03125f);

  // 7) softmax rows (fp8 in) -> P8 = e4m3(256 * P), k-interleaved
  softmax8_k<<<32768, 256, 0, stream>>>(Sl8, P8);

  // 8) out = (P8 @ V8) / 256 + x   (fp8 GEMM, K=2048)
  g8fp8_k<2><<<dim3(8, 8, 16), 512, 0, stream>>>(
      P8, V8, out, x, 2048, 2048, 2048, 1024,
      4194304LL, 2097152LL, SD, SD, 0.00390625f);

  (void)in_sizes; (void)n_in; (void)out_size; (void)ws_size;
}